// Round 5
// baseline (307.045 us; speedup 1.0000x reference)
//
#include <hip/hip_runtime.h>

// HistLoss: per-channel histogram matching + MSE loss.
// C=64, H=W=512, HW=262144, NBINS=256, STRENGTH=100.
//
// R14: FUSION. Evidence: total pinned 188-189us across R9-R13 while
// pass1 moved 47<->60us; histJ/closs each <46.5 (top-5 cutoff) =>
// >=45us of inter-kernel launch gaps + three kernels each near their
// own ~40us floor. R13 also REFUTED the MLP theory: true 16-deep asm
// loads (AGPR-parked, hence VGPR still 44) made pass1 SLOWER (47->58)
// => not latency-bound; asm loads reverted.
// Now 2 kernels: k_bits (pack masks + zero iteration state) and
// k_fused, grid 256 blocks x 1024 thr = 1 block/CU, FULLY RESIDENT;
// block (c,qt) owns channel c, pixel quarter qt (65536 px):
//  P1: pass1 work at 4 blocks/channel: pc partials 8MB (was 32),
//      qtot/minmax/qacc per quarter; nI/nJ from popcount of staged
//      bits. Release: threadfence + atomicAdd(sync1[c]).
//  sync: spin __hip_atomic_load(sync1[c])==4 (all blocks resident =>
//      safe); cross-block reads use device-scope atomic RMWs only.
//  P2: histJ: re-read own J quarter (L2/L3-hot), channel min/max,
//      atomicAdd into ghist[c][256]. Release sync2.
//  P3: closs verbatim with 4 slices (was 16): hsum/cumsum (identical
//      order), analytic remap, f64 loss atomic, done-counter -> out.
// Bit-exact vs R13 except Q_c f32 per-thread grouping (64 px/thread
// vs 32) -> absmax ~1e-9 possible, threshold 2.9e-6.

#define CN    64
#define HWN   262144
#define NB    256
#define NBUK  8192
#define NSL   4                   // pixel slices (blocks) per channel
#define QPIX  (HWN/NSL)           // 65536 pixels per block
#define FT    1024                // fused threads
#define QBUK  (NBUK/4)            // 2048 buckets per block (phase 3)
#define FXS2  268435456.0f        // 2^28 fixed-point scale for sum(v-center)
#define FXSI2 (1.0/268435456.0)

// Pack int32 {0,1} masks to 1 bit/pixel; zero per-iteration state.
__global__ __launch_bounds__(256) void k_bits(
    const int* __restrict__ mI, const int* __restrict__ mJ,
    unsigned char* __restrict__ bI, unsigned char* __restrict__ bJ,
    unsigned* __restrict__ ghist, unsigned* __restrict__ syncbuf,
    double* __restrict__ lossacc, unsigned* __restrict__ donecnt)
{
  const int t = blockIdx.x*256 + threadIdx.x;
  if(blockIdx.x < 64){
    ghist[blockIdx.x*NB + threadIdx.x] = 0u;         // 64 ch x 256 bins
  } else if(blockIdx.x == 64){
    for(int i = threadIdx.x; i < 2048; i += 256) syncbuf[i] = 0u;
    if(threadIdx.x == 0){ *lossacc = 0.0; *donecnt = 0u; }
  }
  const int4* a = (const int4*)mI + 2*t;
  int4 x0 = a[0], x1 = a[1];
  unsigned b = (unsigned)((x0.x>0) | ((x0.y>0)<<1) | ((x0.z>0)<<2) | ((x0.w>0)<<3)
             | ((x1.x>0)<<4) | ((x1.y>0)<<5) | ((x1.z>0)<<6) | ((x1.w>0)<<7));
  const int4* c = (const int4*)mJ + 2*t;
  int4 y0 = c[0], y1 = c[1];
  unsigned d = (unsigned)((y0.x>0) | ((y0.y>0)<<1) | ((y0.z>0)<<2) | ((y0.w>0)<<3)
             | ((y1.x>0)<<4) | ((y1.y>0)<<5) | ((y1.z>0)<<6) | ((y1.w>0)<<7));
  bI[t] = (unsigned char)b;
  bJ[t] = (unsigned char)d;
}

__device__ __forceinline__ void px_i(float v, float& qacc, unsigned* buk){
  int k = (int)(v * (float)NBUK);                    // pow2 scale: exact, monotone
  if(k > NBUK-1) k = NBUK-1;
  float dv = v - ((float)k + 0.5f) * (1.0f/(float)NBUK);
  int fx = (int)rintf(dv * FXS2);                    // |fx| <= 16384
  atomicAdd(&buk[k], ((unsigned)fx << 12) + 1u);
  qacc += dv*dv;
}

__device__ __forceinline__ void grp_p1(float4 vi, float4 vj,
    unsigned bI4, unsigned bJ4, float& qacc, unsigned& mn, unsigned& mx,
    unsigned* buk){
  if(bI4 & 1u) px_i(vi.x, qacc, buk);
  if(bI4 & 2u) px_i(vi.y, qacc, buk);
  if(bI4 & 4u) px_i(vi.z, qacc, buk);
  if(bI4 & 8u) px_i(vi.w, qacc, buk);
  if(bJ4 & 1u){unsigned u=__float_as_uint(vj.x); mn=min(mn,u); mx=max(mx,u);}
  if(bJ4 & 2u){unsigned u=__float_as_uint(vj.y); mn=min(mn,u); mx=max(mx,u);}
  if(bJ4 & 4u){unsigned u=__float_as_uint(vj.z); mn=min(mn,u); mx=max(mx,u);}
  if(bJ4 & 8u){unsigned u=__float_as_uint(vj.w); mn=min(mn,u); mx=max(mx,u);}
}

__global__ __launch_bounds__(FT, 4) void k_fused(
    const float* __restrict__ I, const float* __restrict__ J,
    const unsigned* __restrict__ bI, const unsigned* __restrict__ bJ,
    unsigned* pc, unsigned* qtot, unsigned* mnp, unsigned* mxp,
    unsigned* cip, unsigned* cjp, double* qp, unsigned* ghist,
    unsigned* sync1, unsigned* sync2,
    double* lossacc, unsigned* donecnt, float* out)
{
  const int c = blockIdx.y, qt = blockIdx.x, tid = threadIdx.x;
  const int bid4 = c*NSL + qt;
  const int wid = tid >> 6, lane = tid & 63;
  __shared__ unsigned buk[NBUK];                    // packed (fx<<12)+count
  __shared__ unsigned smbI[QPIX/32], smbJ[QPIX/32]; // 2048 words each
  __shared__ unsigned sred[FT];
  __shared__ unsigned h[NB], hsum[NB];
  __shared__ float cs[NB], hs[NB];
  __shared__ double dred[FT/64];
  __shared__ unsigned umn[FT/64], umx[FT/64], uci[FT/64], ucj[FT/64];
  __shared__ unsigned qsh[16], wsum[FT/64];
  __shared__ double red[FT/64];
  __shared__ float sh_mn, sh_den, sh_st;
  __shared__ unsigned sh_base;

  // ---- stage bits (quarter), popcount for nI/nJ partials ----
  const int qb = qt*(QPIX/32);
  unsigned s0 = bI[qb + tid], s1 = bI[qb + tid + 1024];
  unsigned t0 = bJ[qb + tid], t1 = bJ[qb + tid + 1024];
  smbI[tid] = s0; smbI[tid+1024] = s1;
  smbJ[tid] = t0; smbJ[tid+1024] = t1;
  unsigned ci = __popc(s0) + __popc(s1);
  unsigned cj = __popc(t0) + __popc(t1);
  #pragma unroll
  for(int i = 0; i < 8; i++) buk[i*FT + tid] = 0u;
  __syncthreads();

  // ---- phase 1: I-buckets + J minmax over own quarter ----
  const float4* Ic = (const float4*)(I + (size_t)c*HWN + (size_t)qt*QPIX);
  const float4* Jc = (const float4*)(J + (size_t)c*HWN + (size_t)qt*QPIX);
  float qacc = 0.0f;
  unsigned mn = 0x7F800000u, mx = 0u;
  const int nsh = (tid & 7) * 4;
  const int bw  = tid >> 3;
  #pragma unroll
  for(int g = 0; g < 16; g++){
    float4 vi = Ic[g*FT + tid];
    float4 vj = Jc[g*FT + tid];
    unsigned bI4 = (smbI[g*128 + bw] >> nsh) & 0xFu;
    unsigned bJ4 = (smbJ[g*128 + bw] >> nsh) & 0xFu;
    grp_p1(vi, vj, bI4, bJ4, qacc, mn, mx, buk);
  }
  __syncthreads();                                   // LDS atomics complete

  { unsigned* pcb = pc + (size_t)bid4 * NBUK;        // pc partial (8/thread)
    #pragma unroll
    for(int i = 0; i < 8; i++) pcb[i*FT + tid] = buk[i*FT + tid]; }

  // per-bucket-quarter totals: thread sums 8 buckets, 256-group reduce
  { unsigned csum = 0;
    #pragma unroll
    for(int j = 0; j < 8; j++) csum += buk[tid*8 + j] & 0xFFFu;
    sred[tid] = csum; __syncthreads();
    for(int s = 128; s > 0; s >>= 1){
      if((tid & 255) < s) sred[tid] += sred[tid + s];
      __syncthreads();
    }
    if((tid & 255) == 0) qtot[bid4*4 + (tid >> 8)] = sred[tid];
  }

  double qd = (double)qacc;
  for(int o = 32; o > 0; o >>= 1){
    qd += __shfl_down(qd, o, 64);
    mn  = min(mn, (unsigned)__shfl_down(mn, o, 64));
    mx  = max(mx, (unsigned)__shfl_down(mx, o, 64));
    ci += __shfl_down(ci, o, 64);
    cj += __shfl_down(cj, o, 64);
  }
  if(lane == 0){ dred[wid]=qd; umn[wid]=mn; umx[wid]=mx; uci[wid]=ci; ucj[wid]=cj; }
  __syncthreads();
  if(tid == 0){
    double t = 0.0; unsigned amn=0x7F800000u, amx=0u, aci=0, acj=0;
    for(int w = 0; w < FT/64; w++){
      t += dred[w];
      amn = min(amn, umn[w]); amx = max(amx, umx[w]);
      aci += uci[w]; acj += ucj[w];
    }
    qp[bid4] = t; mnp[bid4] = amn; mxp[bid4] = amx;
    cip[bid4] = aci; cjp[bid4] = acj;
  }

  // ---- release + per-channel sync (4 blocks; grid fully resident) ----
  __syncthreads();
  __threadfence();
  if(tid == 0){
    atomicAdd(&sync1[c*16], 1u);
    while(__hip_atomic_load(&sync1[c*16], __ATOMIC_ACQUIRE,
                            __HIP_MEMORY_SCOPE_AGENT) < 4u)
      __builtin_amdgcn_s_sleep(2);
  }
  __syncthreads();

  // ---- phase 2: channel min/max -> 256-bin J histogram (own quarter) ----
  if(tid < NB) h[tid] = 0u;
  if(tid == 0){
    unsigned amn = 0x7F800000u, amx = 0u;
    for(int i = 0; i < NSL; i++){
      amn = min(amn, atomicOr(&mnp[c*NSL + i], 0u)); // device-scope RMW read
      amx = max(amx, atomicOr(&mxp[c*NSL + i], 0u));
    }
    float mnv = __uint_as_float(amn);
    float rng = __uint_as_float(amx) - mnv;
    sh_mn = mnv;
    sh_den = fmaxf(rng / (float)NB, 1e-12f);         // histJ binning denom
    sh_st  = rng / (float)NB;                        // remap step (unclamped)
  }
  __syncthreads();
  { const float mnv = sh_mn, den = sh_den;
    #pragma unroll
    for(int g = 0; g < 16; g++){
      float4 v = Jc[g*FT + tid];                     // L2/L3-hot re-read
      unsigned b4 = (smbJ[g*128 + bw] >> nsh) & 0xFu;
      if(b4 & 1u){ float bf = floorf((v.x - mnv)/den);
        bf = fminf(fmaxf(bf,0.0f),255.0f); atomicAdd(&h[(int)bf],1u); }
      if(b4 & 2u){ float bf = floorf((v.y - mnv)/den);
        bf = fminf(fmaxf(bf,0.0f),255.0f); atomicAdd(&h[(int)bf],1u); }
      if(b4 & 4u){ float bf = floorf((v.z - mnv)/den);
        bf = fminf(fmaxf(bf,0.0f),255.0f); atomicAdd(&h[(int)bf],1u); }
      if(b4 & 8u){ float bf = floorf((v.w - mnv)/den);
        bf = fminf(fmaxf(bf,0.0f),255.0f); atomicAdd(&h[(int)bf],1u); }
    }
  }
  __syncthreads();
  if(tid < NB) atomicAdd(&ghist[c*NB + tid], h[tid]);
  __threadfence();
  if(tid == 0){
    atomicAdd(&sync2[c*16], 1u);
    while(__hip_atomic_load(&sync2[c*16], __ATOMIC_ACQUIRE,
                            __HIP_MEMORY_SCOPE_AGENT) < 4u)
      __builtin_amdgcn_s_sleep(2);
  }
  __syncthreads();

  // ---- phase 3: closs (4 slices), identical math/order to R13 ----
  if(tid < 16)
    qsh[tid] = atomicOr(&qtot[(c*NSL + (tid>>2))*4 + (tid&3)], 0u);
  if(tid < NB)
    hsum[tid] = atomicAdd(&ghist[c*NB + tid], 0u);
  __syncthreads();
  if(tid == 0){
    unsigned ciw = 0, cjw = 0;
    for(int i = 0; i < NSL; i++){
      ciw += atomicOr(&cip[c*NSL + i], 0u);
      cjw += atomicOr(&cjp[c*NSL + i], 0u);
    }
    float ratio = (float)ciw / (float)cjw;           // nI/nJ in f32, as in ref
    float cum = 0.0f;
    for(int b = 0; b < NB; b++){
      float hh = (float)hsum[b] * ratio;
      hs[b] = hh;
      cum += hh;                                     // sequential f32 == ref rounding
      cs[b] = cum;
    }
    unsigned base = 0;
    for(int s = 0; s < NSL; s++)
      for(int q2 = 0; q2 < qt; q2++) base += qsh[s*4 + q2];
    sh_base = base;
  }
  __syncthreads();

  // own 2 buckets: b0 = qt*QBUK + tid*2 (+0,+1); pc via u64 atomic reads
  unsigned  kk[2] = {0,0};
  long long ss[2] = {0,0};
  for(int sl = 0; sl < NSL; sl++){
    unsigned long long* pcb = (unsigned long long*)
        (pc + (size_t)(c*NSL + sl)*NBUK + qt*QBUK) + tid;
    unsigned long long o = atomicAdd(pcb, 0ULL);     // coherent cross-block read
    unsigned wx = (unsigned)o, wy = (unsigned)(o >> 32);
    kk[0] += wx & 0xFFFu;  ss[0] += (int)wx >> 12;   // sign-extend fx sum
    kk[1] += wy & 0xFFFu;  ss[1] += (int)wy >> 12;
  }
  unsigned run = kk[0] + kk[1];
  unsigned v = run;                                  // wave inclusive scan
  for(int o = 1; o < 64; o <<= 1){
    unsigned t = __shfl_up(v, o, 64);
    if(lane >= o) v += t;
  }
  if(lane == 63) wsum[wid] = v;
  __syncthreads();
  unsigned wbase = 0;
  for(int w = 0; w < wid; w++) wbase += wsum[w];
  unsigned texcl = sh_base + wbase + (v - run);

  float  mnvf = sh_mn, stepf = sh_st;
  double mnvd = (double)mnvf, stepd = (double)stepf;

  float rf0 = (float)(texcl + 1u);                   // left-search start bin
  int lo = 0, hi = NB;
  while(lo < hi){ int mid = (lo + hi) >> 1; if(cs[mid] < rf0) lo = mid + 1; else hi = mid; }
  int bin = (lo > NB-1) ? NB-1 : lo;

  double acc = 0.0;
  unsigned r = texcl;
  #pragma unroll
  for(int j = 0; j < 2; j++){
    unsigned k = kk[j];
    if(k == 0) continue;
    unsigned ra = r + 1u, rb = r + k; r = rb;
    double sval = 0.0;
    while(ra <= rb){
      while(bin < NB-1 && cs[bin] < (float)ra) bin++;
      float csb = cs[bin], hsb = hs[bin];
      unsigned re = (bin == NB-1) ? rb : min(rb, (unsigned)floorf(csb));
      double lovd = (double)csb - (double)hsb;
      double den2 = fmax((double)hsb, 1e-12);
      double ra_d = (double)ra, re_d = (double)re, nn = (double)(re - ra + 1u);
      double rta = (ra_d - lovd)/den2, rtb = (re_d - lovd)/den2;
      if(hsb > 0.0f && rta >= 0.0 && rtb <= 1.0){
        double sumr = 0.5*(ra_d + re_d)*nn;          // arithmetic series of ranks
        sval += nn*(mnvd + (double)bin*stepd) + stepd*(sumr - nn*lovd)/den2;
      } else {                                       // exact per-rank f32 fallback
        for(unsigned rr = ra; rr <= re; rr++){
          float rf = (float)rr;
          float lov = csb - hsb;
          float rt = (rf - lov) / fmaxf(hsb, 1e-12f);
          rt = fminf(fmaxf(rt, 0.0f), 1.0f);
          sval += (double)(mnvf + ((float)bin + rt)*stepf);
        }
      }
      ra = re + 1u;
    }
    double kb   = (double)k;
    double cb   = ((double)(qt*QBUK + tid*2 + j) + 0.5) * (1.0/(double)NBUK);
    double vbar = sval/kb - cb;                      // mean(val) - bucket center
    double S    = (double)ss[j] * FXSI2;             // sum(v - center)
    acc += kb*vbar*vbar - 2.0*vbar*S;
  }
  if(qt == 0 && tid == 0){                           // Q_c once per channel
    double qsum = 0.0;
    for(int qi = 0; qi < NSL; qi++)
      qsum += atomicAdd(&qp[c*NSL + qi], 0.0);
    acc += qsum;
  }
  for(int o = 32; o > 0; o >>= 1) acc += __shfl_down(acc, o, 64);
  if(lane == 0) red[wid] = acc;
  __syncthreads();
  if(tid == 0){
    double t = 0.0;
    for(int w = 0; w < FT/64; w++) t += red[w];
    atomicAdd(lossacc, t);
    __threadfence();
    unsigned old = atomicAdd(donecnt, 1u);
    if(old == (unsigned)(CN*NSL - 1)){               // last block finalizes
      double tot = atomicAdd(lossacc, 0.0);          // coherent read
      out[0] = (float)(tot * (100.0 / (double)((size_t)CN * HWN)));
    }
  }
}

extern "C" void kernel_launch(void* const* d_in, const int* in_sizes, int n_in,
                              void* d_out, int out_size, void* d_ws, size_t ws_size,
                              hipStream_t stream){
  const float* I  = (const float*)d_in[0];
  const float* J  = (const float*)d_in[1];
  const int*   mI = (const int*)d_in[2];
  const int*   mJ = (const int*)d_in[3];
  float* out = (float*)d_out;

  char* base = (char*)d_ws;
  size_t pcB = (size_t)CN * NSL * NBUK * sizeof(unsigned);       // 8 MB
  unsigned* pc      = (unsigned*)base;
  char* p = base + pcB;
  double*   qp      = (double*)p;   p += (size_t)CN*NSL*sizeof(double);
  double*   lossacc = (double*)p;   p += sizeof(double);
  unsigned* qtot    = (unsigned*)p; p += (size_t)CN*NSL*4*sizeof(unsigned);
  unsigned* mnp     = (unsigned*)p; p += (size_t)CN*NSL*sizeof(unsigned);
  unsigned* mxp     = (unsigned*)p; p += (size_t)CN*NSL*sizeof(unsigned);
  unsigned* cip     = (unsigned*)p; p += (size_t)CN*NSL*sizeof(unsigned);
  unsigned* cjp     = (unsigned*)p; p += (size_t)CN*NSL*sizeof(unsigned);
  unsigned* ghist   = (unsigned*)p; p += (size_t)CN*NB*sizeof(unsigned);
  unsigned* syncbuf = (unsigned*)p; p += 2048*sizeof(unsigned);  // sync1|sync2
  unsigned* donecnt = (unsigned*)p; p += sizeof(unsigned);
  size_t off = (size_t)(p - base); off = (off + 15) & ~(size_t)15;
  unsigned char* bIb = (unsigned char*)(base + off);             // 32 KB bitmask
  unsigned char* bJb = bIb + HWN/8;                              // 32 KB bitmask
  unsigned* sync1 = syncbuf;
  unsigned* sync2 = syncbuf + 1024;

  k_bits<<<HWN/(8*256), 256, 0, stream>>>(mI, mJ, bIb, bJb, ghist, syncbuf,
                                          lossacc, donecnt);
  k_fused<<<dim3(NSL, CN), FT, 0, stream>>>(I, J, (const unsigned*)bIb,
                                            (const unsigned*)bJb, pc, qtot,
                                            mnp, mxp, cip, cjp, qp, ghist,
                                            sync1, sync2, lossacc, donecnt, out);
}